// Round 6
// baseline (1650.300 us; speedup 1.0000x reference)
//
#include <hip/hip_runtime.h>

#define N_PTS 8192
#define NSAMP 1024
#define NGRP  32

// Identity asm: makes the asm the SSA producer of x, so the compiler cannot
// re-materialize x from its original global load inside the loop; it must
// keep it live in a VGPR (cap 256 via launch_bounds -> no spill either).
#define PIN(x) asm("" : "+v"(x))

// DPP max step: invalid lanes keep 'old' (=r), identity for max.
#define DPP_MAXSTEP(r, ctrl)                                                  \
  r = fmaxf(r, __int_as_float(__builtin_amdgcn_update_dpp(                    \
          __float_as_int(r), __float_as_int(r), (ctrl), 0xf, 0xf, false)))

// ---------------------------------------------------------------------------
// Kernel 1: farthest point sampling. One block of 512 threads (8 waves) per
// batch; each thread owns 16 consecutive points PINNED in VGPRs.
// Distance rounding matches XLA:CPU's scan-compiled contracted reduce:
//   d = fma(dz,dz, fma(dy,dy, dx*dx))          (bit-exact, DO NOT TOUCH)
// argmax ties -> lowest index. DPP v_max chain + ballot lowest-lane tie.
// One barrier/iter; no global stores in the loop.
// ---------------------------------------------------------------------------
__global__ __launch_bounds__(512, 2) void fps_kernel(
    const float* __restrict__ xyz, float* __restrict__ out_sampled)
{
  #pragma clang fp contract(off)
  const int b = blockIdx.x;
  const int t = threadIdx.x;
  const float* bx = xyz + (size_t)b * N_PTS * 3;

  float px[16], py[16], pz[16], dist[16];
  {
    const float4* src = (const float4*)(bx + t * 48);
    float4 v0 = src[0], v1 = src[1], v2 = src[2];
    float4 v3 = src[3], v4 = src[4], v5 = src[5];
    float4 v6 = src[6], v7 = src[7], v8 = src[8];
    float4 v9 = src[9], v10 = src[10], v11 = src[11];
    px[ 0]=v0.x; py[ 0]=v0.y; pz[ 0]=v0.z;
    px[ 1]=v0.w; py[ 1]=v1.x; pz[ 1]=v1.y;
    px[ 2]=v1.z; py[ 2]=v1.w; pz[ 2]=v2.x;
    px[ 3]=v2.y; py[ 3]=v2.z; pz[ 3]=v2.w;
    px[ 4]=v3.x; py[ 4]=v3.y; pz[ 4]=v3.z;
    px[ 5]=v3.w; py[ 5]=v4.x; pz[ 5]=v4.y;
    px[ 6]=v4.z; py[ 6]=v4.w; pz[ 6]=v5.x;
    px[ 7]=v5.y; py[ 7]=v5.z; pz[ 7]=v5.w;
    px[ 8]=v6.x; py[ 8]=v6.y; pz[ 8]=v6.z;
    px[ 9]=v6.w; py[ 9]=v7.x; pz[ 9]=v7.y;
    px[10]=v7.z; py[10]=v7.w; pz[10]=v8.x;
    px[11]=v8.y; py[11]=v8.z; pz[11]=v8.w;
    px[12]=v9.x; py[12]=v9.y; pz[12]=v9.z;
    px[13]=v9.w; py[13]=v10.x; pz[13]=v10.y;
    px[14]=v10.z; py[14]=v10.w; pz[14]=v11.x;
    px[15]=v11.y; py[15]=v11.z; pz[15]=v11.w;
  }
  #pragma unroll
  for (int r = 0; r < 16; ++r) { PIN(px[r]); PIN(py[r]); PIN(pz[r]); }
  #pragma unroll
  for (int r = 0; r < 16; ++r) dist[r] = 10000000000.0f;

  __shared__ uint2 part[2][8];          // ping-pong (value bits, index)
  __shared__ float out_lds[NSAMP * 3];  // centroid coords, flushed at end

  const int lane = t & 63;
  const int wv   = t >> 6;

  float cx = bx[0], cy = bx[1], cz = bx[2];  // initial centroid = point 0

  for (int it = 0; it < NSAMP; ++it) {
    if (t == 0) {
      out_lds[it * 3 + 0] = cx;
      out_lds[it * 3 + 1] = cy;
      out_lds[it * 3 + 2] = cz;
    }

    float bv = -1.0f;
    #pragma unroll
    for (int r = 0; r < 16; ++r) {
      float dx = px[r] - cx;
      float dy = py[r] - cy;
      float dz = pz[r] - cz;
      float d  = fmaf(dz, dz, fmaf(dy, dy, dx * dx));  // scan-fused rounding
      float nd = fminf(dist[r], d);
      dist[r] = nd;
      bv = fmaxf(bv, nd);
    }
    int bi = t * 16 + 15;
    #pragma unroll
    for (int r = 14; r >= 0; --r) bi = (dist[r] == bv) ? (t * 16 + r) : bi;

    // wave-64 max via DPP chain; lane 63 holds the wave max
    float rmax = bv;
    DPP_MAXSTEP(rmax, 0x111);  // row_shr:1
    DPP_MAXSTEP(rmax, 0x112);  // row_shr:2
    DPP_MAXSTEP(rmax, 0x114);  // row_shr:4
    DPP_MAXSTEP(rmax, 0x118);  // row_shr:8
    DPP_MAXSTEP(rmax, 0x142);  // row_bcast:15
    DPP_MAXSTEP(rmax, 0x143);  // row_bcast:31
    float vmax = __int_as_float(
        __builtin_amdgcn_readlane(__float_as_int(rmax), 63));

    unsigned long long m = __ballot(bv == vmax);
    int L = __ffsll((long long)m) - 1;
    int widx = __builtin_amdgcn_readlane(bi, L);

    const int slot = it & 1;
    if (lane == 0) part[slot][wv] = make_uint2(__float_as_uint(vmax), (unsigned)widx);
    __syncthreads();   // the ONLY barrier; ping-pong makes it WAR-safe

    const uint4* pp = (const uint4*)&part[slot][0];
    uint4 p0 = pp[0], p1 = pp[1], p2 = pp[2], p3 = pp[3];
    float v = __uint_as_float(p0.x); unsigned f = p0.y;
    float w1v = __uint_as_float(p0.z);
    if (w1v > v) { v = w1v; f = p0.w; }
    float w2v = __uint_as_float(p1.x);
    if (w2v > v) { v = w2v; f = p1.y; }
    float w3v = __uint_as_float(p1.z);
    if (w3v > v) { v = w3v; f = p1.w; }
    float w4v = __uint_as_float(p2.x);
    if (w4v > v) { v = w4v; f = p2.y; }
    float w5v = __uint_as_float(p2.z);
    if (w5v > v) { v = w5v; f = p2.w; }
    float w6v = __uint_as_float(p3.x);
    if (w6v > v) { v = w6v; f = p3.y; }
    float w7v = __uint_as_float(p3.z);
    if (w7v > v) { v = w7v; f = p3.w; }

    cx = bx[f * 3 + 0];
    cy = bx[f * 3 + 1];
    cz = bx[f * 3 + 2];
  }

  __syncthreads();
  float* ob = out_sampled + (size_t)b * NSAMP * 3;
  for (int i = t; i < NSAMP * 3; i += 512) ob[i] = out_lds[i];
}

// ---------------------------------------------------------------------------
// Kernel 2: query_ball_point. One wave per centroid, ballot-prefix append,
// early exit once 32 found. EAGER reference rounding (bit-exact, DO NOT TOUCH)
// ---------------------------------------------------------------------------
__global__ __launch_bounds__(256) void ball_kernel(
    const float* __restrict__ xyz, const float* __restrict__ sampled,
    int* __restrict__ gidx)
{
  #pragma clang fp contract(off)
  const float R2 = (float)(0.2 * 0.2);
  int gt = blockIdx.x * 256 + threadIdx.x;
  int w = gt >> 6;                // centroid id, 0..16383
  int lane = gt & 63;
  const int b = w >> 10;
  const float* cp = sampled + (size_t)w * 3;
  float cx = cp[0], cy = cp[1], cz = cp[2];
  float na = ((cx * cx) + (cy * cy)) + (cz * cz);   // eager: plain adds
  const float* bx = xyz + (size_t)b * N_PTS * 3;
  int* out = gidx + (size_t)w * NGRP;

  int cnt = 0;
  int first = 0;
  for (int base = 0; base < N_PTS && cnt < NGRP; base += 64) {
    int p = base + lane;
    float x = bx[p * 3 + 0];
    float y = bx[p * 3 + 1];
    float z = bx[p * 3 + 2];
    float nb  = ((x * x) + (y * y)) + (z * z);      // eager: plain adds
    float dot = fmaf(cz, z, fmaf(cy, y, cx * x));   // Eigen fma chain
    float sq  = (na + nb) - (2.0f * dot);
    bool inr = !(sq > R2);
    unsigned long long m = __ballot(inr);
    if (cnt == 0 && m != 0ull) first = base + (__ffsll(m) - 1);
    int before = __popcll(m & ((1ull << lane) - 1ull));
    int pos = cnt + before;
    if (inr && pos < NGRP) out[pos] = p;
    cnt += __popcll(m);
  }
  if (cnt < NGRP) {
    int q = cnt + lane;
    if (q < NGRP) out[q] = first;
  }
}

// ---------------------------------------------------------------------------
// Kernel 3: gather + MLP(67->64->128->256, relu) + max over 32 points.
// One 256-thread block per centroid. Transposed LDS tiles [c][k], stride 36.
// CONSECUTIVE-j register blocking (2-way L1, 4-way L2/L3):
//   - each ds_read_b128 of points feeds 8/16/32 FMAs (LDS-port pressure /2../4)
//   - weights/biases load as ONE coalesced float4 (VMEM instrs /4)
// All lanes of a wave share the same k-group -> LDS reads are broadcasts.
// pmax reuses fT's LDS region (barrier-separated).
// ---------------------------------------------------------------------------
__global__ __launch_bounds__(256, 4) void mlp_kernel(
    const float* __restrict__ xyz, const float* __restrict__ fea,
    const float* __restrict__ sampled, const int* __restrict__ gidx,
    const float* __restrict__ W1, const float* __restrict__ b1,
    const float* __restrict__ W2, const float* __restrict__ b2,
    const float* __restrict__ W3, const float* __restrict__ b3,
    float* __restrict__ out)
{
  __shared__ float fT[67][36];     // feats^T  [c][k]; later reused as pmax
  __shared__ float h1T[64][36];    // h1^T     [c][k]
  __shared__ float h2T[128][36];   // h2^T     [c][k]
  __shared__ int   sidx[32];
  __shared__ float sc[4];

  const int bs = blockIdx.x;        // b*1024 + s
  const int b  = bs >> 10;
  const int t  = threadIdx.x;

  if (t < 32) sidx[t] = gidx[(size_t)bs * 32 + t];
  if (t < 3)  sc[t] = sampled[(size_t)bs * 3 + t];
  __syncthreads();

  // gather: rel(3) ++ fea(64) -> fT[c][k]
  {
    const int k = t >> 3, c0 = t & 7;
    const int p = sidx[k];
    const float* xp = xyz + ((size_t)b * N_PTS + p) * 3;
    const float* fp = fea + ((size_t)b * N_PTS + p) * 64;
    for (int c = c0; c < 67; c += 8) {
      float v = (c < 3) ? (xp[c] - sc[c]) : fp[c - 3];
      fT[c][k] = v;
    }
  }
  __syncthreads();

  // layer 1: outputs 2j0, 2j0+1 ; 4 points. j0 = t&31, kq = t>>5 (0..7).
  {
    const int j0 = t & 31, kq = t >> 5;
    float a0[4], a1[4];
    float2 bb = *(const float2*)&b1[2 * j0];
    #pragma unroll
    for (int r = 0; r < 4; ++r) { a0[r] = bb.x; a1[r] = bb.y; }
    for (int c = 0; c < 67; ++c) {
      float2 w = *(const float2*)&W1[c * 64 + 2 * j0];
      float4 f = *(const float4*)&fT[c][kq * 4];
      a0[0] = fmaf(f.x, w.x, a0[0]);  a1[0] = fmaf(f.x, w.y, a1[0]);
      a0[1] = fmaf(f.y, w.x, a0[1]);  a1[1] = fmaf(f.y, w.y, a1[1]);
      a0[2] = fmaf(f.z, w.x, a0[2]);  a1[2] = fmaf(f.z, w.y, a1[2]);
      a0[3] = fmaf(f.w, w.x, a0[3]);  a1[3] = fmaf(f.w, w.y, a1[3]);
    }
    float* d0 = &h1T[2 * j0][kq * 4];
    float* d1 = &h1T[2 * j0 + 1][kq * 4];
    #pragma unroll
    for (int r = 0; r < 4; ++r) { d0[r] = fmaxf(a0[r], 0.0f); d1[r] = fmaxf(a1[r], 0.0f); }
  }
  __syncthreads();

  // layer 2: outputs 4j0..4j0+3 ; 4 points. j0 = t&31, kg = t>>5 (0..7).
  {
    const int j0 = t & 31, kg = t >> 5;
    float a[4][4];
    float4 bb = *(const float4*)&b2[4 * j0];
    #pragma unroll
    for (int r = 0; r < 4; ++r) { a[0][r] = bb.x; a[1][r] = bb.y; a[2][r] = bb.z; a[3][r] = bb.w; }
    for (int c = 0; c < 64; ++c) {
      float4 w = *(const float4*)&W2[c * 128 + 4 * j0];
      float4 f = *(const float4*)&h1T[c][kg * 4];
      a[0][0] = fmaf(f.x, w.x, a[0][0]);  a[1][0] = fmaf(f.x, w.y, a[1][0]);
      a[2][0] = fmaf(f.x, w.z, a[2][0]);  a[3][0] = fmaf(f.x, w.w, a[3][0]);
      a[0][1] = fmaf(f.y, w.x, a[0][1]);  a[1][1] = fmaf(f.y, w.y, a[1][1]);
      a[2][1] = fmaf(f.y, w.z, a[2][1]);  a[3][1] = fmaf(f.y, w.w, a[3][1]);
      a[0][2] = fmaf(f.z, w.x, a[0][2]);  a[1][2] = fmaf(f.z, w.y, a[1][2]);
      a[2][2] = fmaf(f.z, w.z, a[2][2]);  a[3][2] = fmaf(f.z, w.w, a[3][2]);
      a[0][3] = fmaf(f.w, w.x, a[0][3]);  a[1][3] = fmaf(f.w, w.y, a[1][3]);
      a[2][3] = fmaf(f.w, w.z, a[2][3]);  a[3][3] = fmaf(f.w, w.w, a[3][3]);
    }
    #pragma unroll
    for (int q = 0; q < 4; ++q) {
      float* d = &h2T[4 * j0 + q][kg * 4];
      #pragma unroll
      for (int r = 0; r < 4; ++r) d[r] = fmaxf(a[q][r], 0.0f);
    }
  }
  __syncthreads();

  // layer 3 + max-pool: outputs 4j0..4j0+3 ; 8 points. j0 = t&63, kq = t>>6.
  float* pmax = &fT[0][0];   // 4*256 floats, reuse (fT dead since layer 1)
  {
    const int j0 = t & 63, kq = t >> 6;
    float a[4][8];
    float4 bb = *(const float4*)&b3[4 * j0];
    #pragma unroll
    for (int r = 0; r < 8; ++r) { a[0][r] = bb.x; a[1][r] = bb.y; a[2][r] = bb.z; a[3][r] = bb.w; }
    for (int c = 0; c < 128; ++c) {
      float4 w = *(const float4*)&W3[c * 256 + 4 * j0];
      const float4* hp = (const float4*)&h2T[c][kq * 8];
      float4 f0 = hp[0], f1 = hp[1];
      #pragma unroll
      for (int q = 0; q < 4; ++q) {
        float wq = (q == 0) ? w.x : (q == 1) ? w.y : (q == 2) ? w.z : w.w;
        a[q][0] = fmaf(f0.x, wq, a[q][0]);
        a[q][1] = fmaf(f0.y, wq, a[q][1]);
        a[q][2] = fmaf(f0.z, wq, a[q][2]);
        a[q][3] = fmaf(f0.w, wq, a[q][3]);
        a[q][4] = fmaf(f1.x, wq, a[q][4]);
        a[q][5] = fmaf(f1.y, wq, a[q][5]);
        a[q][6] = fmaf(f1.z, wq, a[q][6]);
        a[q][7] = fmaf(f1.w, wq, a[q][7]);
      }
    }
    float m[4];
    #pragma unroll
    for (int q = 0; q < 4; ++q) {
      m[q] = a[q][0];
      #pragma unroll
      for (int r = 1; r < 8; ++r) m[q] = fmaxf(m[q], a[q][r]);
    }
    float4* dst = (float4*)&pmax[kq * 256 + 4 * j0];
    *dst = make_float4(m[0], m[1], m[2], m[3]);
  }
  __syncthreads();

  {
    float v = fmaxf(fmaxf(pmax[t], pmax[256 + t]),
                    fmaxf(pmax[512 + t], pmax[768 + t]));
    out[(size_t)bs * 256 + t] = fmaxf(v, 0.0f);   // relu(max) == max(relu)
  }
}

// ---------------------------------------------------------------------------
extern "C" void kernel_launch(void* const* d_in, const int* in_sizes, int n_in,
                              void* d_out, int out_size, void* d_ws, size_t ws_size,
                              hipStream_t stream) {
  const float* xyz = (const float*)d_in[0];
  const float* fea = (const float*)d_in[1];
  const float* W1  = (const float*)d_in[2];
  const float* b1  = (const float*)d_in[3];
  const float* W2  = (const float*)d_in[4];
  const float* b2  = (const float*)d_in[5];
  const float* W3  = (const float*)d_in[6];
  const float* b3  = (const float*)d_in[7];

  float* outp    = (float*)d_out;
  float* sampled = outp;                    // output 0: (16,1024,3)
  float* mlp_out = outp + 16 * 1024 * 3;    // output 1: (16,1024,256)
  int*   gidx    = (int*)d_ws;              // 16384*32 ints = 2 MB scratch

  fps_kernel<<<16, 512, 0, stream>>>(xyz, sampled);
  ball_kernel<<<4096, 256, 0, stream>>>(xyz, sampled, gidx);
  mlp_kernel<<<16384, 256, 0, stream>>>(xyz, fea, sampled, gidx,
                                        W1, b1, W2, b2, W3, b3, mlp_out);
}

// Round 7
// 1523.301 us; speedup vs baseline: 1.0834x; 1.0834x over previous
//
#include <hip/hip_runtime.h>

#define N_PTS 8192
#define NSAMP 1024
#define NGRP  32

// DPP max step: invalid lanes keep 'old' (=r), identity for max.
#define DPP_MAXSTEP(r, ctrl)                                                  \
  r = fmaxf(r, __int_as_float(__builtin_amdgcn_update_dpp(                    \
          __float_as_int(r), __float_as_int(r), (ctrl), 0xf, 0xf, false)))

// ---------------------------------------------------------------------------
// Kernel 1: farthest point sampling. One block of 512 threads (8 waves) per
// batch; each thread owns 16 consecutive points.
// amdgpu_waves_per_eu(2,2): min=max=2 pins the scheduler's occupancy target
// to 2 waves/EU -> 256-VGPR pressure budget, so the 64-float working set
// (px/py/pz/dist) can stay RESIDENT instead of being sunk to L1 reloads
// (R3-R6 all show VGPR_Count 28-48 = sunk; launch_bounds only sets a MIN).
// Distance rounding matches XLA:CPU's scan-compiled contracted reduce:
//   d = fma(dz,dz, fma(dy,dy, dx*dx))          (bit-exact, DO NOT TOUCH)
// argmax ties -> lowest index. DPP v_max chain + ballot lowest-lane tie.
// One barrier/iter; no global stores in the loop.
// ---------------------------------------------------------------------------
__global__
__attribute__((amdgpu_flat_work_group_size(512, 512)))
__attribute__((amdgpu_waves_per_eu(2, 2)))
void fps_kernel(
    const float* __restrict__ xyz, float* __restrict__ out_sampled)
{
  #pragma clang fp contract(off)
  const int b = blockIdx.x;
  const int t = threadIdx.x;
  const float* bx = xyz + (size_t)b * N_PTS * 3;

  float px[16], py[16], pz[16], dist[16];
  {
    const float4* src = (const float4*)(bx + t * 48);
    float4 v0 = src[0], v1 = src[1], v2 = src[2];
    float4 v3 = src[3], v4 = src[4], v5 = src[5];
    float4 v6 = src[6], v7 = src[7], v8 = src[8];
    float4 v9 = src[9], v10 = src[10], v11 = src[11];
    px[ 0]=v0.x; py[ 0]=v0.y; pz[ 0]=v0.z;
    px[ 1]=v0.w; py[ 1]=v1.x; pz[ 1]=v1.y;
    px[ 2]=v1.z; py[ 2]=v1.w; pz[ 2]=v2.x;
    px[ 3]=v2.y; py[ 3]=v2.z; pz[ 3]=v2.w;
    px[ 4]=v3.x; py[ 4]=v3.y; pz[ 4]=v3.z;
    px[ 5]=v3.w; py[ 5]=v4.x; pz[ 5]=v4.y;
    px[ 6]=v4.z; py[ 6]=v4.w; pz[ 6]=v5.x;
    px[ 7]=v5.y; py[ 7]=v5.z; pz[ 7]=v5.w;
    px[ 8]=v6.x; py[ 8]=v6.y; pz[ 8]=v6.z;
    px[ 9]=v6.w; py[ 9]=v7.x; pz[ 9]=v7.y;
    px[10]=v7.z; py[10]=v7.w; pz[10]=v8.x;
    px[11]=v8.y; py[11]=v8.z; pz[11]=v8.w;
    px[12]=v9.x; py[12]=v9.y; pz[12]=v9.z;
    px[13]=v9.w; py[13]=v10.x; pz[13]=v10.y;
    px[14]=v10.z; py[14]=v10.w; pz[14]=v11.x;
    px[15]=v11.y; py[15]=v11.z; pz[15]=v11.w;
  }
  #pragma unroll
  for (int r = 0; r < 16; ++r) dist[r] = 10000000000.0f;

  __shared__ uint2 part[2][8];          // ping-pong (value bits, index)
  __shared__ float out_lds[NSAMP * 3];  // centroid coords, flushed at end

  const int lane = t & 63;
  const int wv   = t >> 6;

  float cx = bx[0], cy = bx[1], cz = bx[2];  // initial centroid = point 0

  for (int it = 0; it < NSAMP; ++it) {
    if (t == 0) {
      out_lds[it * 3 + 0] = cx;
      out_lds[it * 3 + 1] = cy;
      out_lds[it * 3 + 2] = cz;
    }

    float bv = -1.0f;
    #pragma unroll
    for (int r = 0; r < 16; ++r) {
      float dx = px[r] - cx;
      float dy = py[r] - cy;
      float dz = pz[r] - cz;
      float d  = fmaf(dz, dz, fmaf(dy, dy, dx * dx));  // scan-fused rounding
      float nd = fminf(dist[r], d);
      dist[r] = nd;
      bv = fmaxf(bv, nd);
    }
    int bi = t * 16 + 15;
    #pragma unroll
    for (int r = 14; r >= 0; --r) bi = (dist[r] == bv) ? (t * 16 + r) : bi;

    // wave-64 max via DPP chain; lane 63 holds the wave max
    float rmax = bv;
    DPP_MAXSTEP(rmax, 0x111);  // row_shr:1
    DPP_MAXSTEP(rmax, 0x112);  // row_shr:2
    DPP_MAXSTEP(rmax, 0x114);  // row_shr:4
    DPP_MAXSTEP(rmax, 0x118);  // row_shr:8
    DPP_MAXSTEP(rmax, 0x142);  // row_bcast:15
    DPP_MAXSTEP(rmax, 0x143);  // row_bcast:31
    float vmax = __int_as_float(
        __builtin_amdgcn_readlane(__float_as_int(rmax), 63));

    unsigned long long m = __ballot(bv == vmax);
    int L = __ffsll((long long)m) - 1;
    int widx = __builtin_amdgcn_readlane(bi, L);

    const int slot = it & 1;
    if (lane == 0) part[slot][wv] = make_uint2(__float_as_uint(vmax), (unsigned)widx);
    __syncthreads();   // the ONLY barrier; ping-pong makes it WAR-safe

    const uint4* pp = (const uint4*)&part[slot][0];
    uint4 p0 = pp[0], p1 = pp[1], p2 = pp[2], p3 = pp[3];
    float v = __uint_as_float(p0.x); unsigned f = p0.y;
    float w1v = __uint_as_float(p0.z);
    if (w1v > v) { v = w1v; f = p0.w; }
    float w2v = __uint_as_float(p1.x);
    if (w2v > v) { v = w2v; f = p1.y; }
    float w3v = __uint_as_float(p1.z);
    if (w3v > v) { v = w3v; f = p1.w; }
    float w4v = __uint_as_float(p2.x);
    if (w4v > v) { v = w4v; f = p2.y; }
    float w5v = __uint_as_float(p2.z);
    if (w5v > v) { v = w5v; f = p2.w; }
    float w6v = __uint_as_float(p3.x);
    if (w6v > v) { v = w6v; f = p3.y; }
    float w7v = __uint_as_float(p3.z);
    if (w7v > v) { v = w7v; f = p3.w; }

    cx = bx[f * 3 + 0];
    cy = bx[f * 3 + 1];
    cz = bx[f * 3 + 2];
  }

  __syncthreads();
  float* ob = out_sampled + (size_t)b * NSAMP * 3;
  for (int i = t; i < NSAMP * 3; i += 512) ob[i] = out_lds[i];
}

// ---------------------------------------------------------------------------
// Kernel 2: query_ball_point. One wave per centroid, ballot-prefix append,
// early exit once 32 found. EAGER reference rounding (bit-exact, DO NOT TOUCH)
// ---------------------------------------------------------------------------
__global__ __launch_bounds__(256) void ball_kernel(
    const float* __restrict__ xyz, const float* __restrict__ sampled,
    int* __restrict__ gidx)
{
  #pragma clang fp contract(off)
  const float R2 = (float)(0.2 * 0.2);
  int gt = blockIdx.x * 256 + threadIdx.x;
  int w = gt >> 6;                // centroid id, 0..16383
  int lane = gt & 63;
  const int b = w >> 10;
  const float* cp = sampled + (size_t)w * 3;
  float cx = cp[0], cy = cp[1], cz = cp[2];
  float na = ((cx * cx) + (cy * cy)) + (cz * cz);   // eager: plain adds
  const float* bx = xyz + (size_t)b * N_PTS * 3;
  int* out = gidx + (size_t)w * NGRP;

  int cnt = 0;
  int first = 0;
  for (int base = 0; base < N_PTS && cnt < NGRP; base += 64) {
    int p = base + lane;
    float x = bx[p * 3 + 0];
    float y = bx[p * 3 + 1];
    float z = bx[p * 3 + 2];
    float nb  = ((x * x) + (y * y)) + (z * z);      // eager: plain adds
    float dot = fmaf(cz, z, fmaf(cy, y, cx * x));   // Eigen fma chain
    float sq  = (na + nb) - (2.0f * dot);
    bool inr = !(sq > R2);
    unsigned long long m = __ballot(inr);
    if (cnt == 0 && m != 0ull) first = base + (__ffsll(m) - 1);
    int before = __popcll(m & ((1ull << lane) - 1ull));
    int pos = cnt + before;
    if (inr && pos < NGRP) out[pos] = p;
    cnt += __popcll(m);
  }
  if (cnt < NGRP) {
    int q = cnt + lane;
    if (q < NGRP) out[q] = first;
  }
}

// ---------------------------------------------------------------------------
// Kernel 3: gather + MLP(67->64->128->256, relu) + max over 32 points.
// R5 version (668us) — R6's 4-way consecutive-j regressed (707us), reverted.
// One 256-thread block per centroid. Transposed LDS tiles [c][k] (stride 36).
// 2-way j-register-blocking: each ds_read_b128 feeds 8 FMAs.
// ---------------------------------------------------------------------------
__global__ __launch_bounds__(256, 4) void mlp_kernel(
    const float* __restrict__ xyz, const float* __restrict__ fea,
    const float* __restrict__ sampled, const int* __restrict__ gidx,
    const float* __restrict__ W1, const float* __restrict__ b1,
    const float* __restrict__ W2, const float* __restrict__ b2,
    const float* __restrict__ W3, const float* __restrict__ b3,
    float* __restrict__ out)
{
  __shared__ float fT[67][36];     // feats^T  [c][k]
  __shared__ float h1T[64][36];    // h1^T     [c][k]
  __shared__ float h2T[128][36];   // h2^T     [c][k]
  __shared__ float pmax[2][256];   // layer-3 partial maxes per k-half
  __shared__ int   sidx[32];
  __shared__ float sc[4];

  const int bs = blockIdx.x;        // b*1024 + s
  const int b  = bs >> 10;
  const int t  = threadIdx.x;

  if (t < 32) sidx[t] = gidx[(size_t)bs * 32 + t];
  if (t < 3)  sc[t] = sampled[(size_t)bs * 3 + t];
  __syncthreads();

  // gather: rel(3) ++ fea(64) -> fT[c][k]
  {
    const int k = t >> 3, c0 = t & 7;
    const int p = sidx[k];
    const float* xp = xyz + ((size_t)b * N_PTS + p) * 3;
    const float* fp = fea + ((size_t)b * N_PTS + p) * 64;
    for (int c = c0; c < 67; c += 8) {
      float v = (c < 3) ? (xp[c] - sc[c]) : fp[c - 3];
      fT[c][k] = v;
    }
  }
  __syncthreads();

  // layer 1: outputs (j0, j0+32), 4 points each. j0 = t&31, kq = t>>5.
  {
    const int j0 = t & 31, kq = t >> 5;
    float a0[4], a1[4];
    float bb0 = b1[j0], bb1 = b1[j0 + 32];
    #pragma unroll
    for (int r = 0; r < 4; ++r) { a0[r] = bb0; a1[r] = bb1; }
    for (int c = 0; c < 67; ++c) {
      float w0 = W1[c * 64 + j0];
      float w1 = W1[c * 64 + j0 + 32];
      float4 f = *(const float4*)&fT[c][kq * 4];
      a0[0] = fmaf(f.x, w0, a0[0]);  a1[0] = fmaf(f.x, w1, a1[0]);
      a0[1] = fmaf(f.y, w0, a0[1]);  a1[1] = fmaf(f.y, w1, a1[1]);
      a0[2] = fmaf(f.z, w0, a0[2]);  a1[2] = fmaf(f.z, w1, a1[2]);
      a0[3] = fmaf(f.w, w0, a0[3]);  a1[3] = fmaf(f.w, w1, a1[3]);
    }
    float* d0 = &h1T[j0][kq * 4];
    float* d1 = &h1T[j0 + 32][kq * 4];
    #pragma unroll
    for (int r = 0; r < 4; ++r) { d0[r] = fmaxf(a0[r], 0.0f); d1[r] = fmaxf(a1[r], 0.0f); }
  }
  __syncthreads();

  // layer 2: outputs (j0, j0+64), 8 points each. j0 = t&63, kh = t>>6.
  {
    const int j0 = t & 63, kh = t >> 6;
    float a0[8], a1[8];
    float bb0 = b2[j0], bb1 = b2[j0 + 64];
    #pragma unroll
    for (int r = 0; r < 8; ++r) { a0[r] = bb0; a1[r] = bb1; }
    for (int c = 0; c < 64; ++c) {
      float w0 = W2[c * 128 + j0];
      float w1 = W2[c * 128 + j0 + 64];
      const float4* hp = (const float4*)&h1T[c][kh * 8];
      float4 f0 = hp[0], f1 = hp[1];
      a0[0] = fmaf(f0.x, w0, a0[0]);  a1[0] = fmaf(f0.x, w1, a1[0]);
      a0[1] = fmaf(f0.y, w0, a0[1]);  a1[1] = fmaf(f0.y, w1, a1[1]);
      a0[2] = fmaf(f0.z, w0, a0[2]);  a1[2] = fmaf(f0.z, w1, a1[2]);
      a0[3] = fmaf(f0.w, w0, a0[3]);  a1[3] = fmaf(f0.w, w1, a1[3]);
      a0[4] = fmaf(f1.x, w0, a0[4]);  a1[4] = fmaf(f1.x, w1, a1[4]);
      a0[5] = fmaf(f1.y, w0, a0[5]);  a1[5] = fmaf(f1.y, w1, a1[5]);
      a0[6] = fmaf(f1.z, w0, a0[6]);  a1[6] = fmaf(f1.z, w1, a1[6]);
      a0[7] = fmaf(f1.w, w0, a0[7]);  a1[7] = fmaf(f1.w, w1, a1[7]);
    }
    float* d0 = &h2T[j0][kh * 8];
    float* d1 = &h2T[j0 + 64][kh * 8];
    #pragma unroll
    for (int r = 0; r < 8; ++r) { d0[r] = fmaxf(a0[r], 0.0f); d1[r] = fmaxf(a1[r], 0.0f); }
  }
  __syncthreads();

  // layer 3 + max-pool: outputs (j0, j0+128), 16 points each. kh = t>>7.
  {
    const int j0 = t & 127, kh = t >> 7;
    float a0[16], a1[16];
    float bb0 = b3[j0], bb1 = b3[j0 + 128];
    #pragma unroll
    for (int r = 0; r < 16; ++r) { a0[r] = bb0; a1[r] = bb1; }
    for (int c = 0; c < 128; ++c) {
      float w0 = W3[c * 256 + j0];
      float w1 = W3[c * 256 + j0 + 128];
      const float4* hp = (const float4*)&h2T[c][kh * 16];
      #pragma unroll
      for (int q = 0; q < 4; ++q) {
        float4 f = hp[q];
        a0[q*4+0] = fmaf(f.x, w0, a0[q*4+0]);  a1[q*4+0] = fmaf(f.x, w1, a1[q*4+0]);
        a0[q*4+1] = fmaf(f.y, w0, a0[q*4+1]);  a1[q*4+1] = fmaf(f.y, w1, a1[q*4+1]);
        a0[q*4+2] = fmaf(f.z, w0, a0[q*4+2]);  a1[q*4+2] = fmaf(f.z, w1, a1[q*4+2]);
        a0[q*4+3] = fmaf(f.w, w0, a0[q*4+3]);  a1[q*4+3] = fmaf(f.w, w1, a1[q*4+3]);
      }
    }
    float m0 = a0[0], m1 = a1[0];
    #pragma unroll
    for (int r = 1; r < 16; ++r) { m0 = fmaxf(m0, a0[r]); m1 = fmaxf(m1, a1[r]); }
    pmax[kh][j0]       = m0;
    pmax[kh][j0 + 128] = m1;
  }
  __syncthreads();

  {
    float v = fmaxf(pmax[0][t], pmax[1][t]);
    out[(size_t)bs * 256 + t] = fmaxf(v, 0.0f);   // relu(max) == max(relu)
  }
}

// ---------------------------------------------------------------------------
extern "C" void kernel_launch(void* const* d_in, const int* in_sizes, int n_in,
                              void* d_out, int out_size, void* d_ws, size_t ws_size,
                              hipStream_t stream) {
  const float* xyz = (const float*)d_in[0];
  const float* fea = (const float*)d_in[1];
  const float* W1  = (const float*)d_in[2];
  const float* b1  = (const float*)d_in[3];
  const float* W2  = (const float*)d_in[4];
  const float* b2  = (const float*)d_in[5];
  const float* W3  = (const float*)d_in[6];
  const float* b3  = (const float*)d_in[7];

  float* outp    = (float*)d_out;
  float* sampled = outp;                    // output 0: (16,1024,3)
  float* mlp_out = outp + 16 * 1024 * 3;    // output 1: (16,1024,256)
  int*   gidx    = (int*)d_ws;              // 16384*32 ints = 2 MB scratch

  fps_kernel<<<16, 512, 0, stream>>>(xyz, sampled);
  ball_kernel<<<4096, 256, 0, stream>>>(xyz, sampled, gidx);
  mlp_kernel<<<16384, 256, 0, stream>>>(xyz, fea, sampled, gidx,
                                        W1, b1, W2, b2, W3, b3, mlp_out);
}